// Round 1
// baseline (4092.480 us; speedup 1.0000x reference)
//
#include <hip/hip_runtime.h>
#include <hip/hip_bf16.h>
#include <math.h>

#define B_    256
#define T_    60
#define TTOT  80
#define DIN   2048
#define D_    512
#define H_    512
#define G4    2048    // 4*H
#define M1    15360   // B_*T_

// ---------------- zero helper (graph-capture-safe) ----------------
__global__ void k_zero(float* __restrict__ p, int n) {
  int i = blockIdx.x * 256 + threadIdx.x;
  if (i < n) p[i] = 0.f;
}

// ---------------- encoder GEMM: V[m,d] = sum_f video[m,f]*W_enc[d,f] + b_enc[d]
// M=15360, N=512, K=2048. BM=128 BN=64 BK=32, 256 threads, 8x4 outputs/thread.
__global__ __launch_bounds__(256) void k_enc_gemm(const float* __restrict__ A,
                                                  const float* __restrict__ W,
                                                  const float* __restrict__ bias,
                                                  float* __restrict__ C) {
  __shared__ float As[32][128];
  __shared__ float Bs[32][64];
  const int tid = threadIdx.x;
  const int n0 = blockIdx.x * 64;
  const int m0 = blockIdx.y * 128;
  const int tx = tid & 15;   // 4 cols each
  const int ty = tid >> 4;   // 8 rows each
  float acc[8][4];
  #pragma unroll
  for (int i = 0; i < 8; i++)
    #pragma unroll
    for (int j = 0; j < 4; j++) acc[i][j] = 0.f;

  for (int kt = 0; kt < DIN; kt += 32) {
    #pragma unroll
    for (int i = 0; i < 4; i++) {
      int s = tid + i * 256;          // 1024 float4 slots of the 128x32 A tile
      int m = s >> 3;
      int k4 = (s & 7) << 2;
      float4 v = *(const float4*)(A + (size_t)(m0 + m) * DIN + kt + k4);
      As[k4 + 0][m] = v.x; As[k4 + 1][m] = v.y; As[k4 + 2][m] = v.z; As[k4 + 3][m] = v.w;
    }
    #pragma unroll
    for (int i = 0; i < 2; i++) {
      int s = tid + i * 256;          // 512 float4 slots of the 64x32 B tile
      int n = s >> 3;
      int k4 = (s & 7) << 2;
      float4 v = *(const float4*)(W + (size_t)(n0 + n) * DIN + kt + k4);
      Bs[k4 + 0][n] = v.x; Bs[k4 + 1][n] = v.y; Bs[k4 + 2][n] = v.z; Bs[k4 + 3][n] = v.w;
    }
    __syncthreads();
    #pragma unroll
    for (int k = 0; k < 32; k++) {
      float4 a0 = *(const float4*)&As[k][ty * 8];
      float4 a1 = *(const float4*)&As[k][ty * 8 + 4];
      float4 b  = *(const float4*)&Bs[k][tx * 4];
      float av[8] = {a0.x, a0.y, a0.z, a0.w, a1.x, a1.y, a1.z, a1.w};
      float bv[4] = {b.x, b.y, b.z, b.w};
      #pragma unroll
      for (int i = 0; i < 8; i++)
        #pragma unroll
        for (int j = 0; j < 4; j++) acc[i][j] += av[i] * bv[j];
    }
    __syncthreads();
  }
  float4 bb = *(const float4*)(bias + n0 + tx * 4);
  #pragma unroll
  for (int i = 0; i < 8; i++) {
    float4 o;
    o.x = acc[i][0] + bb.x; o.y = acc[i][1] + bb.y;
    o.z = acc[i][2] + bb.z; o.w = acc[i][3] + bb.w;
    *(float4*)(C + (size_t)(m0 + ty * 8 + i) * D_ + n0 + tx * 4) = o;
  }
}

// ---------------- per-feature mean/var partials (deterministic, no atomics)
// 240 blocks, each owns 64 rows; thread owns cols tid and tid+256.
__global__ __launch_bounds__(256) void k_stats_partial(const float* __restrict__ V,
                                                       float* __restrict__ part) {
  const int blk = blockIdx.x;
  const int tid = threadIdx.x;
  float s0 = 0.f, s1 = 0.f, q0 = 0.f, q1 = 0.f;
  const float* p = V + (size_t)blk * 64 * D_;
  for (int r = 0; r < 64; r++) {
    float a = p[(size_t)r * D_ + tid];
    float b = p[(size_t)r * D_ + tid + 256];
    s0 += a; q0 += a * a;
    s1 += b; q1 += b * b;
  }
  part[(size_t)blk * 1024 + tid]             = s0;
  part[(size_t)blk * 1024 + tid + 256]       = s1;
  part[(size_t)blk * 1024 + 512 + tid]       = q0;
  part[(size_t)blk * 1024 + 512 + tid + 256] = q1;
}

__global__ __launch_bounds__(512) void k_stats_final(const float* __restrict__ part,
                                                     float* __restrict__ stats) {
  const int d = threadIdx.x;
  float s = 0.f, q = 0.f;
  for (int r = 0; r < 240; r++) {
    s += part[(size_t)r * 1024 + d];
    q += part[(size_t)r * 1024 + 512 + d];
  }
  float mean = s * (1.f / 15360.f);
  float var  = q * (1.f / 15360.f) - mean * mean;
  stats[d]        = mean;
  stats[512 + d]  = 1.f / sqrtf(var + 1e-5f);
}

// ---------------- normalize (in place) + vscore[b,d] = sum_t vnorm[b,t,d]*w_v[t]
// NOTE: w_h, w_s, b_attn provably cancel in softmax(axis=1) (per-row shift) -> omitted.
__global__ __launch_bounds__(512) void k_norm_vscore(float* __restrict__ V,
                                                     const float* __restrict__ stats,
                                                     const float* __restrict__ gamma,
                                                     const float* __restrict__ beta,
                                                     const float* __restrict__ w_attn,
                                                     float* __restrict__ vscore) {
  const int b = blockIdx.x, d = threadIdx.x;
  __shared__ float wv[T_];
  if (d < T_) wv[d] = w_attn[2 * H_ + d];
  __syncthreads();
  const float mean = stats[d], rstd = stats[512 + d];
  const float ga = gamma[d], be = beta[d];
  float vs = 0.f;
  float* p = V + (size_t)b * T_ * D_ + d;
  for (int t = 0; t < T_; t++) {
    float x = p[(size_t)t * D_];
    float xn = (x - mean) * rstd * ga + be;
    p[(size_t)t * D_] = xn;
    vs += wv[t] * xn;
  }
  vscore[(size_t)b * D_ + d] = vs;
}

// ---------------- alpha[b,:] = softmax(vscore[b,:]) over 512, in place
__global__ __launch_bounds__(512) void k_softmax(float* __restrict__ a) {
  const int b = blockIdx.x, d = threadIdx.x;
  __shared__ float red[8];
  float x = a[(size_t)b * D_ + d];
  float m = x;
  #pragma unroll
  for (int o = 32; o >= 1; o >>= 1) m = fmaxf(m, __shfl_xor(m, o));
  if ((d & 63) == 0) red[d >> 6] = m;
  __syncthreads();
  float M = red[0];
  #pragma unroll
  for (int w = 1; w < 8; w++) M = fmaxf(M, red[w]);
  float e = expf(x - M);
  float s = e;
  #pragma unroll
  for (int o = 32; o >= 1; o >>= 1) s += __shfl_xor(s, o);
  __syncthreads();
  if ((d & 63) == 0) red[d >> 6] = s;
  __syncthreads();
  float S = 0.f;
  #pragma unroll
  for (int w = 0; w < 8; w++) S += red[w];
  a[(size_t)b * D_ + d] = e / S;
}

// ---------------- per-step GEMM: gates[b,n] = [x_t | h] @ [W_ih | W_hh]^T + b_ih + b_hh
// x_t[b,d] = alpha[b,d]*Vnorm[b,t,d] (built on the fly). M=256,N=2048,K=1024(useX)/512.
// BM=32 BN=64 BK=32, 256 threads, 2x4 outputs/thread, grid (32,8)=256 WGs.
__global__ __launch_bounds__(256) void k_step_gemm(const float* __restrict__ V,
                                                   const float* __restrict__ alpha,
                                                   const float* __restrict__ h,
                                                   const float* __restrict__ Wih,
                                                   const float* __restrict__ Whh,
                                                   const float* __restrict__ b_ih,
                                                   const float* __restrict__ b_hh,
                                                   float* __restrict__ gates,
                                                   int t, int useX) {
  __shared__ float As[32][32];
  __shared__ float Bs[32][64];
  const int tid = threadIdx.x;
  const int n0 = blockIdx.x * 64;
  const int m0 = blockIdx.y * 32;
  const int tx = tid & 15;
  const int ty = tid >> 4;
  float acc[2][4] = {{0.f,0.f,0.f,0.f},{0.f,0.f,0.f,0.f}};
  const int K = useX ? 1024 : 512;
  for (int kt = 0; kt < K; kt += 32) {
    {
      int m = tid >> 3;
      int k4 = (tid & 7) << 2;
      int b = m0 + m;
      int kk = kt + k4;
      float4 v;
      if (useX && kt < 512) {
        float4 xv = *(const float4*)(V + ((size_t)b * T_ + t) * D_ + kk);
        float4 av = *(const float4*)(alpha + (size_t)b * D_ + kk);
        v.x = xv.x * av.x; v.y = xv.y * av.y; v.z = xv.z * av.z; v.w = xv.w * av.w;
      } else {
        int kh = useX ? kk - 512 : kk;
        v = *(const float4*)(h + (size_t)b * H_ + kh);
      }
      As[k4 + 0][m] = v.x; As[k4 + 1][m] = v.y; As[k4 + 2][m] = v.z; As[k4 + 3][m] = v.w;
    }
    #pragma unroll
    for (int i = 0; i < 2; i++) {
      int s = tid + i * 256;
      int n = s >> 3;
      int k4 = (s & 7) << 2;
      int kk = kt + k4;
      const float* Wp; int kr;
      if (useX && kt < 512) { Wp = Wih; kr = kk; }
      else { Wp = Whh; kr = useX ? (kk - 512) : kk; }
      float4 v = *(const float4*)(Wp + (size_t)(n0 + n) * H_ + kr);
      Bs[k4 + 0][n] = v.x; Bs[k4 + 1][n] = v.y; Bs[k4 + 2][n] = v.z; Bs[k4 + 3][n] = v.w;
    }
    __syncthreads();
    #pragma unroll
    for (int k = 0; k < 32; k++) {
      float2 a = *(const float2*)&As[k][ty * 2];
      float4 b = *(const float4*)&Bs[k][tx * 4];
      acc[0][0] += a.x * b.x; acc[0][1] += a.x * b.y; acc[0][2] += a.x * b.z; acc[0][3] += a.x * b.w;
      acc[1][0] += a.y * b.x; acc[1][1] += a.y * b.y; acc[1][2] += a.y * b.z; acc[1][3] += a.y * b.w;
    }
    __syncthreads();
  }
  float4 bi = *(const float4*)(b_ih + n0 + tx * 4);
  float4 bh = *(const float4*)(b_hh + n0 + tx * 4);
  #pragma unroll
  for (int i = 0; i < 2; i++) {
    float4 o;
    o.x = acc[i][0] + bi.x + bh.x;
    o.y = acc[i][1] + bi.y + bh.y;
    o.z = acc[i][2] + bi.z + bh.z;
    o.w = acc[i][3] + bi.w + bh.w;
    *(float4*)(gates + (size_t)(m0 + ty * 2 + i) * G4 + n0 + tx * 4) = o;
  }
}

// ---------------- LSTM cell + output write
__device__ __forceinline__ float sigf(float x) { return 1.f / (1.f + expf(-x)); }

__global__ __launch_bounds__(256) void k_cell(const float* __restrict__ gates,
                                              float* __restrict__ h,
                                              float* __restrict__ c,
                                              float* __restrict__ out,
                                              int t) {
  const int gid = blockIdx.x * 256 + threadIdx.x;   // 0..131071
  const int b = gid >> 9, j = gid & 511;
  const float* g = gates + (size_t)b * G4;
  float gi = sigf(g[j]);
  float gf = sigf(g[j + 512]);
  float gg = tanhf(g[j + 1024]);
  float go = sigf(g[j + 1536]);
  float cn = gf * c[gid] + gi * gg;
  float hn = go * tanhf(cn);
  c[gid] = cn;
  h[gid] = hn;
  out[((size_t)b * TTOT + t) * D_ + j] = hn;
}

extern "C" void kernel_launch(void* const* d_in, const int* in_sizes, int n_in,
                              void* d_out, int out_size, void* d_ws, size_t ws_size,
                              hipStream_t stream) {
  const float* video  = (const float*)d_in[0];
  // d_in[1] captions: only its shape (caplen=20) matters -> constant here.
  const float* W_enc  = (const float*)d_in[2];
  const float* b_enc  = (const float*)d_in[3];
  const float* gamma  = (const float*)d_in[4];
  const float* beta   = (const float*)d_in[5];
  const float* w_attn = (const float*)d_in[6];
  // d_in[7] b_attn: cancels in softmax -> unused.
  const float* W_ih   = (const float*)d_in[8];
  const float* W_hh   = (const float*)d_in[9];
  const float* b_ih   = (const float*)d_in[10];
  const float* b_hh   = (const float*)d_in[11];
  float* out = (float*)d_out;

  // workspace layout (floats)
  float* V      = (float*)d_ws;                 // 15360*512   = 7,864,320
  float* part   = V + (size_t)M1 * D_;          // 240*1024    =   245,760
  float* stats  = part + 240 * 1024;            // 1024 (mean|rstd)
  float* vscore = stats + 1024;                 // 256*512 (becomes alpha in place)
  float* gates  = vscore + (size_t)B_ * D_;     // 256*2048
  float* h      = gates + (size_t)B_ * G4;      // 256*512
  float* c      = h + (size_t)B_ * H_;          // 256*512
  // total ~36.1 MB

  // zero h, c (contiguous 262144 floats)
  k_zero<<<1024, 256, 0, stream>>>(h, 2 * B_ * H_);

  k_enc_gemm<<<dim3(8, 120), 256, 0, stream>>>(video, W_enc, b_enc, V);
  k_stats_partial<<<240, 256, 0, stream>>>(V, part);
  k_stats_final<<<1, 512, 0, stream>>>(part, stats);
  k_norm_vscore<<<B_, 512, 0, stream>>>(V, stats, gamma, beta, w_attn, vscore);
  k_softmax<<<B_, 512, 0, stream>>>(vscore);   // vscore now holds alpha

  for (int t = 0; t < TTOT; t++) {
    int useX = (t < T_) ? 1 : 0;
    k_step_gemm<<<dim3(32, 8), 256, 0, stream>>>(V, vscore, h, W_ih, W_hh,
                                                 b_ih, b_hh, gates, t, useX);
    k_cell<<<512, 256, 0, stream>>>(gates, h, c, out, t);
  }
}

// Round 2
// 2676.029 us; speedup vs baseline: 1.5293x; 1.5293x over previous
//
#include <hip/hip_runtime.h>
#include <hip/hip_bf16.h>
#include <math.h>

#define B_    256
#define T_    60
#define TTOT  80
#define DIN   2048
#define D_    512
#define H_    512
#define G4    2048    // 4*H
#define M1    15360   // B_*T_

// ---------------- zero helper (graph-capture-safe) ----------------
__global__ void k_zero(float* __restrict__ p, int n) {
  int i = blockIdx.x * 256 + threadIdx.x;
  if (i < n) p[i] = 0.f;
}

// ---------------- big GEMM: C[m,n] = sum_k A'[m,k]*B[n,k] + bias0[n] (+bias1[n])
// A'[m,k] = A[m,k] * (alpha ? alpha[(m/T_)*K + k] : 1)
// 128x128 tile, BK=32, 256 threads, 8x8 frag/thread, interleaved rows (m=ty+16i).
// LDS rows padded to 36 floats (144B, 16B-aligned) -> conflict-free b128 reads.
__global__ __launch_bounds__(256) void k_big128(const float* __restrict__ A, int lda,
                                                const float* __restrict__ B,
                                                const float* __restrict__ bias0,
                                                const float* __restrict__ bias1,
                                                const float* __restrict__ alpha,
                                                float* __restrict__ C, int N, int K) {
  __shared__ __align__(16) float As[128][36];
  __shared__ __align__(16) float Bs[128][36];
  const int tid = threadIdx.x;
  const int n0 = blockIdx.x * 128;
  const int m0 = blockIdx.y * 128;
  const int tx = tid & 15;
  const int ty = tid >> 4;
  float acc[8][8];
  #pragma unroll
  for (int i = 0; i < 8; i++)
    #pragma unroll
    for (int j = 0; j < 8; j++) acc[i][j] = 0.f;

  for (int kt = 0; kt < K; kt += 32) {
    #pragma unroll
    for (int i = 0; i < 4; i++) {
      int s = tid + i * 256;            // 1024 float4 slots of 128x32 tile
      int m = s >> 3;
      int k4 = (s & 7) << 2;
      float4 v = *(const float4*)(A + (size_t)(m0 + m) * lda + kt + k4);
      if (alpha) {
        int b = (m0 + m) / T_;
        float4 av = *(const float4*)(alpha + (size_t)b * K + kt + k4);
        v.x *= av.x; v.y *= av.y; v.z *= av.z; v.w *= av.w;
      }
      *(float4*)&As[m][k4] = v;
    }
    #pragma unroll
    for (int i = 0; i < 4; i++) {
      int s = tid + i * 256;
      int n = s >> 3;
      int k4 = (s & 7) << 2;
      float4 v = *(const float4*)(B + (size_t)(n0 + n) * K + kt + k4);
      *(float4*)&Bs[n][k4] = v;
    }
    __syncthreads();
    #pragma unroll
    for (int kq = 0; kq < 32; kq += 4) {
      float4 av[8];
      #pragma unroll
      for (int i = 0; i < 8; i++) av[i] = *(const float4*)&As[ty + 16 * i][kq];
      #pragma unroll
      for (int j = 0; j < 8; j++) {
        float4 bv = *(const float4*)&Bs[tx + 16 * j][kq];
        #pragma unroll
        for (int i = 0; i < 8; i++) {
          acc[i][j] = fmaf(av[i].x, bv.x, acc[i][j]);
          acc[i][j] = fmaf(av[i].y, bv.y, acc[i][j]);
          acc[i][j] = fmaf(av[i].z, bv.z, acc[i][j]);
          acc[i][j] = fmaf(av[i].w, bv.w, acc[i][j]);
        }
      }
    }
    __syncthreads();
  }
  #pragma unroll
  for (int j = 0; j < 8; j++) {
    int n = n0 + tx + 16 * j;
    float bb = bias0[n] + (bias1 ? bias1[n] : 0.f);
    #pragma unroll
    for (int i = 0; i < 8; i++) {
      int m = m0 + ty + 16 * i;
      C[(size_t)m * N + n] = acc[i][j] + bb;
    }
  }
}

// ---------------- per-feature mean/var partials (deterministic, no atomics)
__global__ __launch_bounds__(256) void k_stats_partial(const float* __restrict__ V,
                                                       float* __restrict__ part) {
  const int blk = blockIdx.x;
  const int tid = threadIdx.x;
  float s0 = 0.f, s1 = 0.f, q0 = 0.f, q1 = 0.f;
  const float* p = V + (size_t)blk * 64 * D_;
  for (int r = 0; r < 64; r++) {
    float a = p[(size_t)r * D_ + tid];
    float b = p[(size_t)r * D_ + tid + 256];
    s0 += a; q0 += a * a;
    s1 += b; q1 += b * b;
  }
  part[(size_t)blk * 1024 + tid]             = s0;
  part[(size_t)blk * 1024 + tid + 256]       = s1;
  part[(size_t)blk * 1024 + 512 + tid]       = q0;
  part[(size_t)blk * 1024 + 512 + tid + 256] = q1;
}

__global__ __launch_bounds__(512) void k_stats_final(const float* __restrict__ part,
                                                     float* __restrict__ stats) {
  const int d = threadIdx.x;
  float s = 0.f, q = 0.f;
  for (int r = 0; r < 240; r++) {
    s += part[(size_t)r * 1024 + d];
    q += part[(size_t)r * 1024 + 512 + d];
  }
  float mean = s * (1.f / 15360.f);
  float var  = q * (1.f / 15360.f) - mean * mean;
  stats[d]        = mean;
  stats[512 + d]  = 1.f / sqrtf(var + 1e-5f);
}

// ---------------- normalize (in place) + vscore[b,d] = sum_t vnorm[b,t,d]*w_v[t]
// w_h, w_s, b_attn provably cancel in softmax(axis=1) (per-row shift) -> omitted.
__global__ __launch_bounds__(512) void k_norm_vscore(float* __restrict__ V,
                                                     const float* __restrict__ stats,
                                                     const float* __restrict__ gamma,
                                                     const float* __restrict__ beta,
                                                     const float* __restrict__ w_attn,
                                                     float* __restrict__ vscore) {
  const int b = blockIdx.x, d = threadIdx.x;
  __shared__ float wv[T_];
  if (d < T_) wv[d] = w_attn[2 * H_ + d];
  __syncthreads();
  const float mean = stats[d], rstd = stats[512 + d];
  const float ga = gamma[d], be = beta[d];
  float vs = 0.f;
  float* p = V + (size_t)b * T_ * D_ + d;
  for (int t = 0; t < T_; t++) {
    float x = p[(size_t)t * D_];
    float xn = (x - mean) * rstd * ga + be;
    p[(size_t)t * D_] = xn;
    vs += wv[t] * xn;
  }
  vscore[(size_t)b * D_ + d] = vs;
}

// ---------------- alpha[b,:] = softmax over 512, in place
__global__ __launch_bounds__(512) void k_softmax(float* __restrict__ a) {
  const int b = blockIdx.x, d = threadIdx.x;
  __shared__ float red[8];
  float x = a[(size_t)b * D_ + d];
  float m = x;
  #pragma unroll
  for (int o = 32; o >= 1; o >>= 1) m = fmaxf(m, __shfl_xor(m, o));
  if ((d & 63) == 0) red[d >> 6] = m;
  __syncthreads();
  float M = red[0];
  #pragma unroll
  for (int w = 1; w < 8; w++) M = fmaxf(M, red[w]);
  float e = expf(x - M);
  float s = e;
  #pragma unroll
  for (int o = 32; o >= 1; o >>= 1) s += __shfl_xor(s, o);
  __syncthreads();
  if ((d & 63) == 0) red[d >> 6] = s;
  __syncthreads();
  float S = 0.f;
  #pragma unroll
  for (int w = 0; w < 8; w++) S += red[w];
  a[(size_t)b * D_ + d] = e / S;
}

// ---------------- step GEMM v2: gates[b,n] = h@W_hh^T + (t<T ? xW[b*T+t,n] : b_ih+b_hh)
// M=256,N=2048,K=512. BM=BN=32, BK=32, 256 threads, 2x2 frag, grid (64,8)=512 WGs.
__global__ __launch_bounds__(256) void k_step2(const float* __restrict__ h,
                                               const float* __restrict__ Whh,
                                               const float* __restrict__ xW,
                                               const float* __restrict__ b_ih,
                                               const float* __restrict__ b_hh,
                                               float* __restrict__ gates, int t) {
  __shared__ __align__(16) float As[32][36];
  __shared__ __align__(16) float Bs[32][36];
  const int tid = threadIdx.x;
  const int n0 = blockIdx.x * 32;
  const int m0 = blockIdx.y * 32;
  const int tx = tid & 15;
  const int ty = tid >> 4;
  float acc[2][2] = {{0.f, 0.f}, {0.f, 0.f}};
  for (int kt = 0; kt < H_; kt += 32) {
    {
      int m = tid >> 3;
      int k4 = (tid & 7) << 2;
      *(float4*)&As[m][k4] = *(const float4*)(h   + (size_t)(m0 + m) * H_ + kt + k4);
      *(float4*)&Bs[m][k4] = *(const float4*)(Whh + (size_t)(n0 + m) * H_ + kt + k4);
    }
    __syncthreads();
    #pragma unroll
    for (int kq = 0; kq < 32; kq += 4) {
      float4 a0 = *(const float4*)&As[ty][kq];
      float4 a1 = *(const float4*)&As[ty + 16][kq];
      float4 b0 = *(const float4*)&Bs[tx][kq];
      float4 b1 = *(const float4*)&Bs[tx + 16][kq];
      acc[0][0] = fmaf(a0.x,b0.x,fmaf(a0.y,b0.y,fmaf(a0.z,b0.z,fmaf(a0.w,b0.w,acc[0][0]))));
      acc[0][1] = fmaf(a0.x,b1.x,fmaf(a0.y,b1.y,fmaf(a0.z,b1.z,fmaf(a0.w,b1.w,acc[0][1]))));
      acc[1][0] = fmaf(a1.x,b0.x,fmaf(a1.y,b0.y,fmaf(a1.z,b0.z,fmaf(a1.w,b0.w,acc[1][0]))));
      acc[1][1] = fmaf(a1.x,b1.x,fmaf(a1.y,b1.y,fmaf(a1.z,b1.z,fmaf(a1.w,b1.w,acc[1][1]))));
    }
    __syncthreads();
  }
  #pragma unroll
  for (int i = 0; i < 2; i++) {
    int m = m0 + ty + 16 * i;
    #pragma unroll
    for (int j = 0; j < 2; j++) {
      int n = n0 + tx + 16 * j;
      float base = (t < T_) ? xW[((size_t)m * T_ + t) * G4 + n]
                            : (b_ih[n] + b_hh[n]);
      gates[(size_t)m * G4 + n] = acc[i][j] + base;
    }
  }
}

// ---------------- fallback per-step GEMM (R1, used if ws too small for xW)
__global__ __launch_bounds__(256) void k_step_gemm(const float* __restrict__ V,
                                                   const float* __restrict__ alpha,
                                                   const float* __restrict__ h,
                                                   const float* __restrict__ Wih,
                                                   const float* __restrict__ Whh,
                                                   const float* __restrict__ b_ih,
                                                   const float* __restrict__ b_hh,
                                                   float* __restrict__ gates,
                                                   int t, int useX) {
  __shared__ float As[32][32];
  __shared__ float Bs[32][64];
  const int tid = threadIdx.x;
  const int n0 = blockIdx.x * 64;
  const int m0 = blockIdx.y * 32;
  const int tx = tid & 15;
  const int ty = tid >> 4;
  float acc[2][4] = {{0.f,0.f,0.f,0.f},{0.f,0.f,0.f,0.f}};
  const int K = useX ? 1024 : 512;
  for (int kt = 0; kt < K; kt += 32) {
    {
      int m = tid >> 3;
      int k4 = (tid & 7) << 2;
      int b = m0 + m;
      int kk = kt + k4;
      float4 v;
      if (useX && kt < 512) {
        float4 xv = *(const float4*)(V + ((size_t)b * T_ + t) * D_ + kk);
        float4 av = *(const float4*)(alpha + (size_t)b * D_ + kk);
        v.x = xv.x * av.x; v.y = xv.y * av.y; v.z = xv.z * av.z; v.w = xv.w * av.w;
      } else {
        int kh = useX ? kk - 512 : kk;
        v = *(const float4*)(h + (size_t)b * H_ + kh);
      }
      As[k4 + 0][m] = v.x; As[k4 + 1][m] = v.y; As[k4 + 2][m] = v.z; As[k4 + 3][m] = v.w;
    }
    #pragma unroll
    for (int i = 0; i < 2; i++) {
      int s = tid + i * 256;
      int n = s >> 3;
      int k4 = (s & 7) << 2;
      int kk = kt + k4;
      const float* Wp; int kr;
      if (useX && kt < 512) { Wp = Wih; kr = kk; }
      else { Wp = Whh; kr = useX ? (kk - 512) : kk; }
      float4 v = *(const float4*)(Wp + (size_t)(n0 + n) * H_ + kr);
      Bs[k4 + 0][n] = v.x; Bs[k4 + 1][n] = v.y; Bs[k4 + 2][n] = v.z; Bs[k4 + 3][n] = v.w;
    }
    __syncthreads();
    #pragma unroll
    for (int k = 0; k < 32; k++) {
      float2 a = *(const float2*)&As[k][ty * 2];
      float4 b = *(const float4*)&Bs[k][tx * 4];
      acc[0][0] += a.x * b.x; acc[0][1] += a.x * b.y; acc[0][2] += a.x * b.z; acc[0][3] += a.x * b.w;
      acc[1][0] += a.y * b.x; acc[1][1] += a.y * b.y; acc[1][2] += a.y * b.z; acc[1][3] += a.y * b.w;
    }
    __syncthreads();
  }
  float4 bi = *(const float4*)(b_ih + n0 + tx * 4);
  float4 bh = *(const float4*)(b_hh + n0 + tx * 4);
  #pragma unroll
  for (int i = 0; i < 2; i++) {
    float4 o;
    o.x = acc[i][0] + bi.x + bh.x;
    o.y = acc[i][1] + bi.y + bh.y;
    o.z = acc[i][2] + bi.z + bh.z;
    o.w = acc[i][3] + bi.w + bh.w;
    *(float4*)(gates + (size_t)(m0 + ty * 2 + i) * G4 + n0 + tx * 4) = o;
  }
}

// ---------------- LSTM cell + output write
__device__ __forceinline__ float sigf(float x) { return 1.f / (1.f + expf(-x)); }

__global__ __launch_bounds__(256) void k_cell(const float* __restrict__ gates,
                                              float* __restrict__ h,
                                              float* __restrict__ c,
                                              float* __restrict__ out,
                                              int t) {
  const int gid = blockIdx.x * 256 + threadIdx.x;   // 0..131071
  const int b = gid >> 9, j = gid & 511;
  const float* g = gates + (size_t)b * G4;
  float gi = sigf(g[j]);
  float gf = sigf(g[j + 512]);
  float gg = tanhf(g[j + 1024]);
  float go = sigf(g[j + 1536]);
  float cn = gf * c[gid] + gi * gg;
  float hn = go * tanhf(cn);
  c[gid] = cn;
  h[gid] = hn;
  out[((size_t)b * TTOT + t) * D_ + j] = hn;
}

extern "C" void kernel_launch(void* const* d_in, const int* in_sizes, int n_in,
                              void* d_out, int out_size, void* d_ws, size_t ws_size,
                              hipStream_t stream) {
  const float* video  = (const float*)d_in[0];
  const float* W_enc  = (const float*)d_in[2];
  const float* b_enc  = (const float*)d_in[3];
  const float* gamma  = (const float*)d_in[4];
  const float* beta   = (const float*)d_in[5];
  const float* w_attn = (const float*)d_in[6];
  const float* W_ih   = (const float*)d_in[8];
  const float* W_hh   = (const float*)d_in[9];
  const float* b_ih   = (const float*)d_in[10];
  const float* b_hh   = (const float*)d_in[11];
  float* out = (float*)d_out;

  // workspace layout (floats)
  float* V     = (float*)d_ws;                  // 15360*512
  size_t off   = (size_t)M1 * D_;
  float* part  = V + off;      off += 240 * 1024;
  float* stats = (float*)d_ws + off; off += 1024;
  float* alpha = (float*)d_ws + off; off += (size_t)B_ * D_;
  float* gates = (float*)d_ws + off; off += (size_t)B_ * G4;
  float* h     = (float*)d_ws + off; off += (size_t)B_ * H_;
  float* c     = (float*)d_ws + off; off += (size_t)B_ * H_;
  float* xW    = (float*)d_ws + off;            // 15360*2048 (optional)
  size_t need_xw = (off + (size_t)M1 * G4) * sizeof(float);
  const bool useXW = (ws_size >= need_xw);

  k_zero<<<1024, 256, 0, stream>>>(h, 2 * B_ * H_);

  // encoder GEMM: V = video @ W_enc^T + b_enc   (M=15360,N=512,K=2048)
  k_big128<<<dim3(4, 120), 256, 0, stream>>>(video, DIN, W_enc, b_enc, nullptr,
                                             nullptr, V, D_, DIN);
  k_stats_partial<<<240, 256, 0, stream>>>(V, part);
  k_stats_final<<<1, 512, 0, stream>>>(part, stats);
  k_norm_vscore<<<B_, 512, 0, stream>>>(V, stats, gamma, beta, w_attn, alpha);
  k_softmax<<<B_, 512, 0, stream>>>(alpha);

  if (useXW) {
    // xW = (alpha ⊙ V) @ W_ih^T + b_ih + b_hh   (M=15360,N=2048,K=512)
    k_big128<<<dim3(16, 120), 256, 0, stream>>>(V, D_, W_ih, b_ih, b_hh,
                                                alpha, xW, G4, D_);
    for (int t = 0; t < TTOT; t++) {
      k_step2<<<dim3(64, 8), 256, 0, stream>>>(h, W_hh, xW, b_ih, b_hh, gates, t);
      k_cell<<<512, 256, 0, stream>>>(gates, h, c, out, t);
    }
  } else {
    for (int t = 0; t < TTOT; t++) {
      int useX = (t < T_) ? 1 : 0;
      k_step_gemm<<<dim3(32, 8), 256, 0, stream>>>(V, alpha, h, W_ih, W_hh,
                                                   b_ih, b_hh, gates, t, useX);
      k_cell<<<512, 256, 0, stream>>>(gates, h, c, out, t);
    }
  }
}

// Round 3
// 1348.619 us; speedup vs baseline: 3.0346x; 1.9843x over previous
//
#include <hip/hip_runtime.h>
#include <hip/hip_bf16.h>
#include <math.h>

#define B_    256
#define T_    60
#define TTOT  80
#define DIN   2048
#define D_    512
#define H_    512
#define G4    2048    // 4*H
#define M1    15360   // B_*T_

typedef __bf16 bf16x8 __attribute__((ext_vector_type(8)));
typedef __bf16 bf16x4 __attribute__((ext_vector_type(4)));
typedef float  f32x4  __attribute__((ext_vector_type(4)));

// ---------------- zero helper ----------------
__global__ void k_zero_u32(unsigned* __restrict__ p, int n) {
  int i = blockIdx.x * 256 + threadIdx.x;
  if (i < n) p[i] = 0u;
}

// ---------------- f32 -> bf16 convert (4 elems/thread) ----------------
__global__ __launch_bounds__(256) void k_cvt(const float* __restrict__ s,
                                             __bf16* __restrict__ d, int n) {
  int i = (blockIdx.x * 256 + threadIdx.x) * 4;
  if (i >= n) return;
  float4 f = *(const float4*)(s + i);
  bf16x4 v;
  v[0] = (__bf16)f.x; v[1] = (__bf16)f.y; v[2] = (__bf16)f.z; v[3] = (__bf16)f.w;
  *(bf16x4*)(d + i) = v;
}

__global__ void k_bsum(const float* __restrict__ a, const float* __restrict__ b,
                       float* __restrict__ d) {
  int i = blockIdx.x * 256 + threadIdx.x;
  if (i < G4) d[i] = a[i] + b[i];
}

// ---------------- MFMA GEMM: C[m,n] = sum_k bf16(A'[m,k]) * B[n,k]  (+bias)
// A f32 row-major [M][lda]; A' = alpha ? alpha[(m/T_)][k]*A : A.  B bf16 [N][K].
// 128x128 tile, BK=64, 4 waves (2x2), wave = 4x4 tiles of 16x16x32.
// LDS: bf16 [128][64], 16B-granule XOR swizzle g^(row&7) -> <=2-way conflicts.
template<bool ALPHA, bool OUTBF>
__global__ __launch_bounds__(256) void k_mm(const float* __restrict__ A, int lda,
                                            const __bf16* __restrict__ Bm,
                                            const float* __restrict__ bias0,
                                            const float* __restrict__ bias1,
                                            const float* __restrict__ alpha,
                                            void* __restrict__ Cout,
                                            int N, int K) {
  __shared__ __bf16 As[128 * 64];
  __shared__ __bf16 Bs[128 * 64];
  const int tid  = threadIdx.x;
  const int lane = tid & 63;
  const int wv   = tid >> 6;
  const int wm   = wv >> 1, wn = wv & 1;
  const int la   = lane & 15, lk = lane >> 4;
  const int n0   = blockIdx.x * 128;
  const int m0   = blockIdx.y * 128;

  f32x4 acc[4][4];
  #pragma unroll
  for (int i = 0; i < 4; i++)
    #pragma unroll
    for (int j = 0; j < 4; j++) acc[i][j] = (f32x4){0.f, 0.f, 0.f, 0.f};

  for (int kt = 0; kt < K; kt += 64) {
    __syncthreads();
    #pragma unroll
    for (int i = 0; i < 4; i++) {          // stage A (f32 -> bf16)
      int idx = tid + i * 256;             // 128 rows x 8 granules
      int row = idx >> 3, gk = idx & 7;
      const float* src = A + (size_t)(m0 + row) * lda + kt + gk * 8;
      float4 f0 = *(const float4*)src;
      float4 f1 = *(const float4*)(src + 4);
      if (ALPHA) {
        int b = (m0 + row) / T_;
        const float* ap = alpha + (size_t)b * K + kt + gk * 8;
        float4 a0 = *(const float4*)ap;
        float4 a1 = *(const float4*)(ap + 4);
        f0.x *= a0.x; f0.y *= a0.y; f0.z *= a0.z; f0.w *= a0.w;
        f1.x *= a1.x; f1.y *= a1.y; f1.z *= a1.z; f1.w *= a1.w;
      }
      bf16x8 v;
      v[0] = (__bf16)f0.x; v[1] = (__bf16)f0.y; v[2] = (__bf16)f0.z; v[3] = (__bf16)f0.w;
      v[4] = (__bf16)f1.x; v[5] = (__bf16)f1.y; v[6] = (__bf16)f1.z; v[7] = (__bf16)f1.w;
      *(bf16x8*)(As + row * 64 + ((gk ^ (row & 7)) << 3)) = v;
    }
    #pragma unroll
    for (int i = 0; i < 4; i++) {          // stage B (bf16 direct)
      int idx = tid + i * 256;
      int row = idx >> 3, gk = idx & 7;
      bf16x8 v = *(const bf16x8*)(Bm + (size_t)(n0 + row) * K + kt + gk * 8);
      *(bf16x8*)(Bs + row * 64 + ((gk ^ (row & 7)) << 3)) = v;
    }
    __syncthreads();
    #pragma unroll
    for (int ks = 0; ks < 2; ks++) {
      bf16x8 af[4], bf[4];
      #pragma unroll
      for (int i = 0; i < 4; i++) {
        int row = wm * 64 + i * 16 + la;
        af[i] = *(const bf16x8*)(As + row * 64 + (((ks * 4 + lk) ^ (row & 7)) << 3));
      }
      #pragma unroll
      for (int j = 0; j < 4; j++) {
        int row = wn * 64 + j * 16 + la;
        bf[j] = *(const bf16x8*)(Bs + row * 64 + (((ks * 4 + lk) ^ (row & 7)) << 3));
      }
      #pragma unroll
      for (int i = 0; i < 4; i++)
        #pragma unroll
        for (int j = 0; j < 4; j++)
          acc[i][j] = __builtin_amdgcn_mfma_f32_16x16x32_bf16(af[i], bf[j], acc[i][j], 0, 0, 0);
    }
  }
  // epilogue: D layout col=lane&15, row=(lane>>4)*4+reg  [m89-verified]
  #pragma unroll
  for (int j = 0; j < 4; j++) {
    int col = n0 + wn * 64 + j * 16 + la;
    float bb = bias0[col] + (bias1 ? bias1[col] : 0.f);
    #pragma unroll
    for (int i = 0; i < 4; i++) {
      int rbase = m0 + wm * 64 + i * 16 + lk * 4;
      #pragma unroll
      for (int r = 0; r < 4; r++) {
        float v = acc[i][j][r] + bb;
        if (OUTBF) ((__bf16*)Cout)[(size_t)(rbase + r) * N + col] = (__bf16)v;
        else       ((float*)Cout)[(size_t)(rbase + r) * N + col] = v;
      }
    }
  }
}

// ---------------- per-feature mean/var partials ----------------
__global__ __launch_bounds__(256) void k_stats_partial(const float* __restrict__ V,
                                                       float* __restrict__ part) {
  const int blk = blockIdx.x;
  const int tid = threadIdx.x;
  float s0 = 0.f, s1 = 0.f, q0 = 0.f, q1 = 0.f;
  const float* p = V + (size_t)blk * 64 * D_;
  for (int r = 0; r < 64; r++) {
    float a = p[(size_t)r * D_ + tid];
    float b = p[(size_t)r * D_ + tid + 256];
    s0 += a; q0 += a * a;
    s1 += b; q1 += b * b;
  }
  part[(size_t)blk * 1024 + tid]             = s0;
  part[(size_t)blk * 1024 + tid + 256]       = s1;
  part[(size_t)blk * 1024 + 512 + tid]       = q0;
  part[(size_t)blk * 1024 + 512 + tid + 256] = q1;
}

__global__ __launch_bounds__(512) void k_stats_final(const float* __restrict__ part,
                                                     float* __restrict__ stats) {
  const int d = threadIdx.x;
  float s = 0.f, q = 0.f;
  for (int r = 0; r < 240; r++) {
    s += part[(size_t)r * 1024 + d];
    q += part[(size_t)r * 1024 + 512 + d];
  }
  float mean = s * (1.f / 15360.f);
  float var  = q * (1.f / 15360.f) - mean * mean;
  stats[d]        = mean;
  stats[512 + d]  = 1.f / sqrtf(var + 1e-5f);
}

// ---------------- normalize (in place) + vscore ----------------
// w_h, w_s, b_attn cancel in softmax(axis=1) (per-row shift) -> omitted.
__global__ __launch_bounds__(512) void k_norm_vscore(float* __restrict__ V,
                                                     const float* __restrict__ stats,
                                                     const float* __restrict__ gamma,
                                                     const float* __restrict__ beta,
                                                     const float* __restrict__ w_attn,
                                                     float* __restrict__ vscore) {
  const int b = blockIdx.x, d = threadIdx.x;
  __shared__ float wv[T_];
  if (d < T_) wv[d] = w_attn[2 * H_ + d];
  __syncthreads();
  const float mean = stats[d], rstd = stats[512 + d];
  const float ga = gamma[d], be = beta[d];
  float vs = 0.f;
  float* p = V + (size_t)b * T_ * D_ + d;
  for (int t = 0; t < T_; t++) {
    float x = p[(size_t)t * D_];
    float xn = (x - mean) * rstd * ga + be;
    p[(size_t)t * D_] = xn;
    vs += wv[t] * xn;
  }
  vscore[(size_t)b * D_ + d] = vs;
}

// ---------------- alpha = softmax over 512, in place ----------------
__global__ __launch_bounds__(512) void k_softmax(float* __restrict__ a) {
  const int b = blockIdx.x, d = threadIdx.x;
  __shared__ float red[8];
  float x = a[(size_t)b * D_ + d];
  float m = x;
  #pragma unroll
  for (int o = 32; o >= 1; o >>= 1) m = fmaxf(m, __shfl_xor(m, o));
  if ((d & 63) == 0) red[d >> 6] = m;
  __syncthreads();
  float M = red[0];
  #pragma unroll
  for (int w = 1; w < 8; w++) M = fmaxf(M, red[w]);
  float e = expf(x - M);
  float s = e;
  #pragma unroll
  for (int o = 32; o >= 1; o >>= 1) s += __shfl_xor(s, o);
  __syncthreads();
  if ((d & 63) == 0) red[d >> 6] = s;
  __syncthreads();
  float S = 0.f;
  #pragma unroll
  for (int w = 0; w < 8; w++) S += red[w];
  a[(size_t)b * D_ + d] = e / S;
}

// ---------------- fused recurrence step: gates MFMA + LSTM cell ----------------
// Each wave owns a 16x16 (b,j) tile; computes all 4 gate n-tiles (j,+512,+1024,+1536)
// so i/f/g/o are register-local in the D layout (col=j=lane&15, row=b=(lane>>4)*4+r).
// 512 waves = 128 WGs. W_hh streamed bf16 from L2. h double-buffered bf16.
__device__ __forceinline__ float sigf(float x) { return 1.f / (1.f + expf(-x)); }

__global__ __launch_bounds__(256) void k_step(const __bf16* __restrict__ hin,
                                              const __bf16* __restrict__ Whh,
                                              const __bf16* __restrict__ xW,
                                              const float* __restrict__ bsum,
                                              float* __restrict__ c,
                                              __bf16* __restrict__ hout,
                                              float* __restrict__ out, int t) {
  const int tid  = threadIdx.x;
  const int lane = tid & 63;
  const int wv   = blockIdx.x * 4 + (tid >> 6);   // 0..511
  const int b0   = (wv >> 5) * 16;                // 16 b-tiles
  const int j0   = (wv & 31) * 16;                // 32 j-tiles
  const int la   = lane & 15, lk = lane >> 4;

  f32x4 acc[4];
  #pragma unroll
  for (int g = 0; g < 4; g++) acc[g] = (f32x4){0.f, 0.f, 0.f, 0.f};

  const __bf16* ap = hin + (size_t)(b0 + la) * H_ + lk * 8;
  #pragma unroll 4
  for (int ks = 0; ks < 16; ks++) {
    bf16x8 a = *(const bf16x8*)(ap + ks * 32);
    #pragma unroll
    for (int g = 0; g < 4; g++) {
      bf16x8 b = *(const bf16x8*)(Whh + (size_t)(g * H_ + j0 + la) * H_ + ks * 32 + lk * 8);
      acc[g] = __builtin_amdgcn_mfma_f32_16x16x32_bf16(a, b, acc[g], 0, 0, 0);
    }
  }

  const int j = j0 + la;
  #pragma unroll
  for (int r = 0; r < 4; r++) {
    const int b = b0 + lk * 4 + r;
    float gi, gf, gg, go;
    if (t < T_) {
      const __bf16* xp = xW + ((size_t)b * T_ + t) * G4;
      gi = acc[0][r] + (float)xp[j];
      gf = acc[1][r] + (float)xp[j + 512];
      gg = acc[2][r] + (float)xp[j + 1024];
      go = acc[3][r] + (float)xp[j + 1536];
    } else {
      gi = acc[0][r] + bsum[j];
      gf = acc[1][r] + bsum[j + 512];
      gg = acc[2][r] + bsum[j + 1024];
      go = acc[3][r] + bsum[j + 1536];
    }
    gi = sigf(gi); gf = sigf(gf); gg = tanhf(gg); go = sigf(go);
    const size_t ci = (size_t)b * H_ + j;
    float cn = gf * c[ci] + gi * gg;
    c[ci] = cn;
    float hn = go * tanhf(cn);
    hout[ci] = (__bf16)hn;
    out[((size_t)b * TTOT + t) * D_ + j] = hn;
  }
}

extern "C" void kernel_launch(void* const* d_in, const int* in_sizes, int n_in,
                              void* d_out, int out_size, void* d_ws, size_t ws_size,
                              hipStream_t stream) {
  const float* video  = (const float*)d_in[0];
  const float* W_enc  = (const float*)d_in[2];
  const float* b_enc  = (const float*)d_in[3];
  const float* gamma  = (const float*)d_in[4];
  const float* beta   = (const float*)d_in[5];
  const float* w_attn = (const float*)d_in[6];
  const float* W_ih   = (const float*)d_in[8];
  const float* W_hh   = (const float*)d_in[9];
  const float* b_ih   = (const float*)d_in[10];
  const float* b_hh   = (const float*)d_in[11];
  float* out = (float*)d_out;

  // workspace layout (float-sized units; total ~103 MB)
  float*  base  = (float*)d_ws;
  float*  V     = base;                         size_t off = (size_t)M1 * D_;
  float*  part  = base + off;                   off += 240 * 1024;
  float*  stats = base + off;                   off += 1024;
  float*  alpha = base + off;                   off += (size_t)B_ * D_;
  float*  c     = base + off;                   off += (size_t)B_ * H_;
  __bf16* h0    = (__bf16*)(base + off);        off += (size_t)B_ * H_ / 2;
  __bf16* h1    = (__bf16*)(base + off);        off += (size_t)B_ * H_ / 2;
  __bf16* xWbf  = (__bf16*)(base + off);        off += (size_t)M1 * G4 / 2;
  __bf16* Wencb = (__bf16*)(base + off);        off += (size_t)D_ * DIN / 2;
  __bf16* Wihb  = (__bf16*)(base + off);        off += (size_t)G4 * H_ / 2;
  __bf16* Whhb  = (__bf16*)(base + off);        off += (size_t)G4 * H_ / 2;
  float*  bsum  = base + off;                   off += G4;

  // weight conversions + bias sum
  k_cvt<<<dim3(D_ * DIN / 1024), 256, 0, stream>>>(W_enc, Wencb, D_ * DIN);
  k_cvt<<<dim3(G4 * H_ / 1024), 256, 0, stream>>>(W_ih, Wihb, G4 * H_);
  k_cvt<<<dim3(G4 * H_ / 1024), 256, 0, stream>>>(W_hh, Whhb, G4 * H_);
  k_bsum<<<dim3(G4 / 256), 256, 0, stream>>>(b_ih, b_hh, bsum);

  // zero c + h0 + h1 (contiguous: 512KB + 256KB + 256KB = 262144 u32)
  k_zero_u32<<<dim3(1024), 256, 0, stream>>>((unsigned*)c, 262144);

  // encoder GEMM: V = video @ W_enc^T + b_enc  (M=15360,N=512,K=2048)
  k_mm<false, false><<<dim3(4, 120), 256, 0, stream>>>(
      video, DIN, Wencb, b_enc, nullptr, nullptr, V, D_, DIN);

  k_stats_partial<<<240, 256, 0, stream>>>(V, part);
  k_stats_final<<<1, 512, 0, stream>>>(part, stats);
  k_norm_vscore<<<B_, 512, 0, stream>>>(V, stats, gamma, beta, w_attn, alpha);
  k_softmax<<<B_, 512, 0, stream>>>(alpha);

  // xW = (alpha ⊙ V) @ W_ih^T + b_ih + b_hh  (M=15360,N=2048,K=512), bf16 out
  k_mm<true, true><<<dim3(16, 120), 256, 0, stream>>>(
      V, D_, Wihb, b_ih, b_hh, alpha, (void*)xWbf, G4, D_);

  for (int t = 0; t < TTOT; t++) {
    const __bf16* hi = (t & 1) ? h1 : h0;
    __bf16*       ho = (t & 1) ? h0 : h1;
    k_step<<<128, 256, 0, stream>>>(hi, Whhb, xWbf, bsum, c, ho, out, t);
  }
}